// Round 6
// baseline (54.155 us; speedup 1.0000x reference)
//
#include <hip/hip_runtime.h>
#include <stdint.h>

// DN4 image-to-class via bf16 MFMA, round 6: fully fused main kernel.
// prep:      normalize all descriptors -> bf16 [vec][64].
// dn4_fused: one block per (class, query image). 4 waves x 64 queries each.
//            Support (1280x64) streamed as 10 double-buffered 16KB LDS tiles
//            (global_load_lds, pre-swizzled source). Per-lane top-3 lattices,
//            c15-lane merge, then 3 in-block bitonic sorts -> top-64 output.

#define C_CLS 5
#define SHOTS 5
#define DIM 64
#define HW 256
#define NQ 75
#define K1 3
#define K2 64
#define M_TOT 1280
#define NIT 10                // 128-row support tiles
#define QG 4                  // 16-query groups per wave

using bf16x8 = __attribute__((ext_vector_type(8))) short;
using f32x4  = __attribute__((ext_vector_type(4))) float;

typedef __attribute__((address_space(1))) const unsigned int GU32;
typedef __attribute__((address_space(3))) unsigned int LU32;

__device__ __forceinline__ void gload16(const void* g, void* l) {
    __builtin_amdgcn_global_load_lds((GU32*)g, (LU32*)l, 16, 0, 0);
}

// XOR swizzle on byte offset within a [128 rows][128 B] tile (involution)
#define SWZ(o) ((o) ^ ((((o) >> 7) & 7) << 4))

__device__ inline unsigned short f2bf(float x) {
    uint32_t u = __float_as_uint(x);
    u += 0x7FFF + ((u >> 16) & 1);          // RNE
    return (unsigned short)(u >> 16);
}

// branchless sorted-triple insert; t2 reads old t1, t1 reads old t0
__device__ __forceinline__ void ins3(float v, float& t0, float& t1, float& t2) {
    t2 = __builtin_amdgcn_fmed3f(v, t1, t2);
    t1 = __builtin_amdgcn_fmed3f(v, t0, t1);
    t0 = fmaxf(t0, v);
}

// 400 blocks x 256 threads; each wave: 16 descriptors x 4 d-groups of 16.
__global__ __launch_bounds__(256)
void prep(const float* __restrict__ support, const float* __restrict__ query,
          unsigned short* __restrict__ Sn, unsigned short* __restrict__ Qn) {
    const int tid  = threadIdx.x;
    const int wv   = tid >> 6, lane = tid & 63;
    const int dg   = lane >> 4, dl = lane & 15;
    const int bid  = blockIdx.x;
    const float* src;
    unsigned short* dst;
    if (bid < NQ * 4) {
        const int b    = bid >> 2;
        const int desc = (bid & 3) * 64 + wv * 16 + dl;
        src = query + (size_t)b * DIM * HW + desc;
        dst = Qn + ((size_t)b * HW + desc) * DIM + dg * 16;
    } else {
        const int sb   = bid - NQ * 4;
        const int cs   = sb >> 2;                      // c*SHOTS + s
        const int desc = (sb & 3) * 64 + wv * 16 + dl;
        const int c = cs / SHOTS, s = cs % SHOTS;
        src = support + (size_t)cs * DIM * HW + desc;
        dst = Sn + ((size_t)c * M_TOT + s * HW + desc) * DIM + dg * 16;
    }
    float v[16];
    float nrm = 0.f;
#pragma unroll
    for (int i = 0; i < 16; ++i) {
        const float x = src[(dg * 16 + i) * HW];
        v[i] = x; nrm = fmaf(x, x, nrm);
    }
    nrm += __shfl_xor(nrm, 16, 64);
    nrm += __shfl_xor(nrm, 32, 64);
    const float inv = rsqrtf(nrm);
    uint32_t p[8];
#pragma unroll
    for (int j = 0; j < 8; ++j)
        p[j] = (uint32_t)f2bf(v[2 * j] * inv) | ((uint32_t)f2bf(v[2 * j + 1] * inv) << 16);
    const uint4 w0 = {p[0], p[1], p[2], p[3]}, w1 = {p[4], p[5], p[6], p[7]};
    ((uint4*)dst)[0] = w0;
    ((uint4*)dst)[1] = w1;
}

// grid 375: bid = c*NQ + b
__global__ __launch_bounds__(256)
void dn4_fused(const unsigned short* __restrict__ Sn,
               const unsigned short* __restrict__ Qn,
               float* __restrict__ out) {
    __shared__ unsigned short sB[2][128 * DIM];   // 2 x 16 KB, double-buffered

    const int tid  = threadIdx.x;
    const int lane = tid & 63, w = tid >> 6;
    const int c15  = lane & 15, kg = lane >> 4;
    const int bid  = blockIdx.x;
    const int c    = bid / NQ, b = bid % NQ;

    // ---- A fragments: this wave's 64 queries (4 groups of 16), gathered once ----
    bf16x8 aq[QG][2];
    const int q0 = b * HW + w * (QG * 16);
#pragma unroll
    for (int g = 0; g < QG; ++g) {
        const unsigned short* qp = Qn + (size_t)(q0 + g * 16 + c15) * DIM + kg * 8;
        aq[g][0] = *(const bf16x8*)qp;          // k 0..31
        aq[g][1] = *(const bf16x8*)(qp + 32);   // k 32..63
    }

    float t0[QG][4], t1[QG][4], t2[QG][4];
#pragma unroll
    for (int g = 0; g < QG; ++g)
#pragma unroll
        for (int r = 0; r < 4; ++r) { t0[g][r] = -2.f; t1[g][r] = -2.f; t2[g][r] = -2.f; }

    const int sw   = (c15 & 7) << 4;
    const int off0 = (kg * 16) ^ sw;
    const int off1 = (kg * 16 + 64) ^ sw;
    const int rowb = c15 * 128;

    const char* tb0 = (const char*)(Sn + (size_t)c * M_TOT * DIM);

    // ---- prologue: stage tile 0 into buf 0 ----
#pragma unroll
    for (int rep = 0; rep < 4; ++rep) {
        const int o = rep * 4096 + tid * 16;
        gload16(tb0 + SWZ(o), (char*)sB[0] + rep * 4096 + w * 1024);
    }
    __syncthreads();

    int cur = 0;
    for (int it = 0; it < NIT; ++it) {
        if (it < NIT - 1) {                       // issue next tile BEFORE compute
            const char* tb = tb0 + (size_t)(it + 1) * 16384;
#pragma unroll
            for (int rep = 0; rep < 4; ++rep) {
                const int o = rep * 4096 + tid * 16;
                gload16(tb + SWZ(o), (char*)sB[cur ^ 1] + rep * 4096 + w * 1024);
            }
        }
#pragma unroll
        for (int ns = 0; ns < 8; ++ns) {
            const char* rp = (const char*)sB[cur] + rowb + ns * 2048;
            const bf16x8 b0 = *(const bf16x8*)(rp + off0);
            const bf16x8 b1 = *(const bf16x8*)(rp + off1);
#pragma unroll
            for (int g = 0; g < QG; ++g) {
                f32x4 acc = {0.f, 0.f, 0.f, 0.f};
                acc = __builtin_amdgcn_mfma_f32_16x16x32_bf16(aq[g][0], b0, acc, 0, 0, 0);
                acc = __builtin_amdgcn_mfma_f32_16x16x32_bf16(aq[g][1], b1, acc, 0, 0, 0);
#pragma unroll
                for (int r = 0; r < 4; ++r)
                    ins3(acc[r], t0[g][r], t1[g][r], t2[g][r]);
            }
        }
        __syncthreads();                          // drains staging vmcnt too
        cur ^= 1;
    }

    // ---- merge across the 16 support-column lanes ----
#pragma unroll
    for (int g = 0; g < QG; ++g)
#pragma unroll
        for (int r = 0; r < 4; ++r)
#pragma unroll
            for (int off = 1; off < 16; off <<= 1) {
                const float o0 = __shfl_xor(t0[g][r], off, 64);
                const float o1 = __shfl_xor(t1[g][r], off, 64);
                const float o2 = __shfl_xor(t2[g][r], off, 64);
                ins3(o0, t0[g][r], t1[g][r], t2[g][r]);
                ins3(o1, t0[g][r], t1[g][r], t2[g][r]);
                ins3(o2, t0[g][r], t1[g][r], t2[g][r]);
            }

    // ---- dump per-query triples to LDS (overlay on tile memory) ----
    float* sr = (float*)sB;            // 3 * 256 floats
    float* xb = sr + K1 * HW;          // 256-float bitonic exchange buffer
    if (c15 == 0) {
#pragma unroll
        for (int g = 0; g < QG; ++g)
#pragma unroll
            for (int r = 0; r < 4; ++r) {
                const int qloc = w * (QG * 16) + g * 16 + kg * 4 + r;
                sr[0 * HW + qloc] = t0[g][r];
                sr[1 * HW + qloc] = t1[g][r];
                sr[2 * HW + qloc] = t2[g][r];
            }
    }
    __syncthreads();

    // ---- 3 bitonic descending sorts of 256 (shfl for j<64, LDS for j>=64) ----
    const size_t obase = (size_t)bid * K1 * K2;
    for (int rk = 0; rk < K1; ++rk) {
        float v = sr[rk * HW + tid];
#pragma unroll
        for (int kk = 2; kk <= HW; kk <<= 1) {
#pragma unroll
            for (int j = kk >> 1; j > 0; j >>= 1) {
                const bool keep_max = (((tid & kk) == 0) == ((tid & j) == 0));
                float pw;
                if (j >= 64) {
                    xb[tid] = v;
                    __syncthreads();
                    pw = xb[tid ^ j];
                    __syncthreads();
                } else {
                    pw = __shfl_xor(v, j, 64);
                }
                v = keep_max ? fmaxf(v, pw) : fminf(v, pw);
            }
        }
        if (tid < K2) out[obase + (size_t)rk * K2 + tid] = v;
    }
}

extern "C" void kernel_launch(void* const* d_in, const int* in_sizes, int n_in,
                              void* d_out, int out_size, void* d_ws, size_t ws_size,
                              hipStream_t stream) {
    const float* support = (const float*)d_in[0];
    const float* query   = (const float*)d_in[1];
    float* out = (float*)d_out;

    char* ws = (char*)d_ws;
    unsigned short* Sn = (unsigned short*)ws;              //   819,200 B
    unsigned short* Qn = (unsigned short*)(ws + 819200);   // 2,457,600 B (3.3 MB total)

    prep     <<<dim3(400),          dim3(256), 0, stream>>>(support, query, Sn, Qn);
    dn4_fused<<<dim3(C_CLS * NQ),   dim3(256), 0, stream>>>(Sn, Qn, out);
}

// Round 7
// 48.733 us; speedup vs baseline: 1.1113x; 1.1113x over previous
//
#include <hip/hip_runtime.h>
#include <stdint.h>

// DN4 image-to-class via bf16 MFMA, round 7: fused, 512-thread blocks.
// prep:      normalize all descriptors -> bf16 [vec][64].
// dn4_fused: one block per (class, query image); 8 waves x 32 queries.
//            Support (1280x64) streamed as 10 double-buffered 16KB LDS tiles
//            (global_load_lds, pre-swizzled source). Per-lane top-3 lattices,
//            c15-lane merge, then parallel bitonic sorts -> top-64 output.

#define C_CLS 5
#define SHOTS 5
#define DIM 64
#define HW 256
#define NQ 75
#define K1 3
#define K2 64
#define M_TOT 1280
#define NIT 10                // 128-row support tiles
#define QG 2                  // 16-query groups per wave

using bf16x8 = __attribute__((ext_vector_type(8))) short;
using f32x4  = __attribute__((ext_vector_type(4))) float;

typedef __attribute__((address_space(1))) const unsigned int GU32;
typedef __attribute__((address_space(3))) unsigned int LU32;

__device__ __forceinline__ void gload16(const void* g, void* l) {
    __builtin_amdgcn_global_load_lds((GU32*)g, (LU32*)l, 16, 0, 0);
}

// XOR swizzle on byte offset within a [128 rows][128 B] tile (involution)
#define SWZ(o) ((o) ^ ((((o) >> 7) & 7) << 4))

__device__ inline unsigned short f2bf(float x) {
    uint32_t u = __float_as_uint(x);
    u += 0x7FFF + ((u >> 16) & 1);          // RNE
    return (unsigned short)(u >> 16);
}

// branchless sorted-triple insert; t2 reads old t1, t1 reads old t0
__device__ __forceinline__ void ins3(float v, float& t0, float& t1, float& t2) {
    t2 = __builtin_amdgcn_fmed3f(v, t1, t2);
    t1 = __builtin_amdgcn_fmed3f(v, t0, t1);
    t0 = fmaxf(t0, v);
}

// 400 blocks x 256 threads; each wave: 16 descriptors x 4 d-groups of 16.
__global__ __launch_bounds__(256)
void prep(const float* __restrict__ support, const float* __restrict__ query,
          unsigned short* __restrict__ Sn, unsigned short* __restrict__ Qn) {
    const int tid  = threadIdx.x;
    const int wv   = tid >> 6, lane = tid & 63;
    const int dg   = lane >> 4, dl = lane & 15;
    const int bid  = blockIdx.x;
    const float* src;
    unsigned short* dst;
    if (bid < NQ * 4) {
        const int b    = bid >> 2;
        const int desc = (bid & 3) * 64 + wv * 16 + dl;
        src = query + (size_t)b * DIM * HW + desc;
        dst = Qn + ((size_t)b * HW + desc) * DIM + dg * 16;
    } else {
        const int sb   = bid - NQ * 4;
        const int cs   = sb >> 2;                      // c*SHOTS + s
        const int desc = (sb & 3) * 64 + wv * 16 + dl;
        const int c = cs / SHOTS, s = cs % SHOTS;
        src = support + (size_t)cs * DIM * HW + desc;
        dst = Sn + ((size_t)c * M_TOT + s * HW + desc) * DIM + dg * 16;
    }
    float v[16];
    float nrm = 0.f;
#pragma unroll
    for (int i = 0; i < 16; ++i) {
        const float x = src[(dg * 16 + i) * HW];
        v[i] = x; nrm = fmaf(x, x, nrm);
    }
    nrm += __shfl_xor(nrm, 16, 64);
    nrm += __shfl_xor(nrm, 32, 64);
    const float inv = rsqrtf(nrm);
    uint32_t p[8];
#pragma unroll
    for (int j = 0; j < 8; ++j)
        p[j] = (uint32_t)f2bf(v[2 * j] * inv) | ((uint32_t)f2bf(v[2 * j + 1] * inv) << 16);
    const uint4 w0 = {p[0], p[1], p[2], p[3]}, w1 = {p[4], p[5], p[6], p[7]};
    ((uint4*)dst)[0] = w0;
    ((uint4*)dst)[1] = w1;
}

// grid 375: bid = c*NQ + b. 512 threads = 8 waves x 32 queries.
__global__ __launch_bounds__(512)
void dn4_fused(const unsigned short* __restrict__ Sn,
               const unsigned short* __restrict__ Qn,
               float* __restrict__ out) {
    __shared__ unsigned short sB[2][128 * DIM];   // 2 x 16 KB, double-buffered
    __shared__ float sr[K1 * HW];                 // per-query top-3
    __shared__ float xb[2 * HW];                  // bitonic exchange, per half

    const int tid  = threadIdx.x;
    const int lane = tid & 63, w = tid >> 6;      // w in 0..7
    const int c15  = lane & 15, kg = lane >> 4;
    const int bid  = blockIdx.x;
    const int c    = bid / NQ, b = bid % NQ;

    // ---- A fragments: this wave's 32 queries (2 groups of 16), gathered once ----
    bf16x8 aq[QG][2];
    const int q0 = b * HW + w * (QG * 16);
#pragma unroll
    for (int g = 0; g < QG; ++g) {
        const unsigned short* qp = Qn + (size_t)(q0 + g * 16 + c15) * DIM + kg * 8;
        aq[g][0] = *(const bf16x8*)qp;          // k 0..31
        aq[g][1] = *(const bf16x8*)(qp + 32);   // k 32..63
    }

    float t0[QG][4], t1[QG][4], t2[QG][4];
#pragma unroll
    for (int g = 0; g < QG; ++g)
#pragma unroll
        for (int r = 0; r < 4; ++r) { t0[g][r] = -2.f; t1[g][r] = -2.f; t2[g][r] = -2.f; }

    const int sw   = (c15 & 7) << 4;
    const int off0 = (kg * 16) ^ sw;
    const int off1 = (kg * 16 + 64) ^ sw;
    const int rowb = c15 * 128;

    const char* tb0 = (const char*)(Sn + (size_t)c * M_TOT * DIM);

    // ---- prologue: stage tile 0 into buf 0 (512 threads x 16B x 2 reps) ----
#pragma unroll
    for (int rep = 0; rep < 2; ++rep) {
        const int o = rep * 8192 + tid * 16;
        gload16(tb0 + SWZ(o), (char*)sB[0] + rep * 8192 + w * 1024);
    }
    __syncthreads();

    int cur = 0;
    for (int it = 0; it < NIT; ++it) {
        if (it < NIT - 1) {                       // issue next tile BEFORE compute
            const char* tb = tb0 + (size_t)(it + 1) * 16384;
#pragma unroll
            for (int rep = 0; rep < 2; ++rep) {
                const int o = rep * 8192 + tid * 16;
                gload16(tb + SWZ(o), (char*)sB[cur ^ 1] + rep * 8192 + w * 1024);
            }
        }
#pragma unroll
        for (int ns = 0; ns < 8; ++ns) {
            const char* rp = (const char*)sB[cur] + rowb + ns * 2048;
            const bf16x8 b0 = *(const bf16x8*)(rp + off0);
            const bf16x8 b1 = *(const bf16x8*)(rp + off1);
#pragma unroll
            for (int g = 0; g < QG; ++g) {
                f32x4 acc = {0.f, 0.f, 0.f, 0.f};
                acc = __builtin_amdgcn_mfma_f32_16x16x32_bf16(aq[g][0], b0, acc, 0, 0, 0);
                acc = __builtin_amdgcn_mfma_f32_16x16x32_bf16(aq[g][1], b1, acc, 0, 0, 0);
#pragma unroll
                for (int r = 0; r < 4; ++r)
                    ins3(acc[r], t0[g][r], t1[g][r], t2[g][r]);
            }
        }
        __syncthreads();                          // drains staging vmcnt too
        cur ^= 1;
    }

    // ---- merge across the 16 support-column lanes ----
#pragma unroll
    for (int g = 0; g < QG; ++g)
#pragma unroll
        for (int r = 0; r < 4; ++r)
#pragma unroll
            for (int off = 1; off < 16; off <<= 1) {
                const float o0 = __shfl_xor(t0[g][r], off, 64);
                const float o1 = __shfl_xor(t1[g][r], off, 64);
                const float o2 = __shfl_xor(t2[g][r], off, 64);
                ins3(o0, t0[g][r], t1[g][r], t2[g][r]);
                ins3(o1, t0[g][r], t1[g][r], t2[g][r]);
                ins3(o2, t0[g][r], t1[g][r], t2[g][r]);
            }

    // ---- dump per-query triples to LDS ----
    if (c15 == 0) {
#pragma unroll
        for (int g = 0; g < QG; ++g)
#pragma unroll
            for (int r = 0; r < 4; ++r) {
                const int qloc = w * (QG * 16) + g * 16 + kg * 4 + r;
                sr[0 * HW + qloc] = t0[g][r];
                sr[1 * HW + qloc] = t1[g][r];
                sr[2 * HW + qloc] = t2[g][r];
            }
    }
    __syncthreads();

    // ---- parallel bitonic descending sorts: halves do (rank0 || rank1), then (rank2 || dummy) ----
    const size_t obase = (size_t)bid * K1 * K2;
    const int half = tid >> 8, t256 = tid & 255;
    float* xbh = xb + half * HW;
#pragma unroll
    for (int pass = 0; pass < 2; ++pass) {
        const int rk = pass * 2 + half;           // 0,1 then 2,3(dummy)
        float v = sr[(rk < K1 ? rk : 0) * HW + t256];
#pragma unroll
        for (int kk = 2; kk <= HW; kk <<= 1) {
#pragma unroll
            for (int j = kk >> 1; j > 0; j >>= 1) {
                const bool keep_max = (((t256 & kk) == 0) == ((t256 & j) == 0));
                float pw;
                if (j >= 64) {
                    xbh[t256] = v;
                    __syncthreads();
                    pw = xbh[t256 ^ j];
                    __syncthreads();
                } else {
                    pw = __shfl_xor(v, j, 64);
                }
                v = keep_max ? fmaxf(v, pw) : fminf(v, pw);
            }
        }
        if (rk < K1 && t256 < K2) out[obase + (size_t)rk * K2 + t256] = v;
    }
}

extern "C" void kernel_launch(void* const* d_in, const int* in_sizes, int n_in,
                              void* d_out, int out_size, void* d_ws, size_t ws_size,
                              hipStream_t stream) {
    const float* support = (const float*)d_in[0];
    const float* query   = (const float*)d_in[1];
    float* out = (float*)d_out;

    char* ws = (char*)d_ws;
    unsigned short* Sn = (unsigned short*)ws;              //   819,200 B
    unsigned short* Qn = (unsigned short*)(ws + 819200);   // 2,457,600 B (3.3 MB total)

    prep     <<<dim3(400),        dim3(256), 0, stream>>>(support, query, Sn, Qn);
    dn4_fused<<<dim3(C_CLS * NQ), dim3(512), 0, stream>>>(Sn, Qn, out);
}